// Round 17
// baseline (536.703 us; speedup 1.0000x reference)
//
#include <hip/hip_runtime.h>
#include <hip/hip_fp16.h>
#include <math.h>

typedef unsigned long long u64;
typedef unsigned int u32;

#define Hh 960
#define Ww 1280
#define Bb 2
#define Kk 1024
#define Pp 256
#define KP1 1025
#define NSEG 4
#define LISTCAP 131072
#define PR 28
#define PS 57
#define ZLD 1040                         /* padded Z row stride (16B-aligned) */
#define CANDCAP 8192
#define KEYCAP 256
static const size_t ZB = (size_t)KP1*ZLD;  // per-batch Z floats

static const size_t HWp = (size_t)Hh * Ww;   // one plane
static const size_t PLn = HWp * Bb;          // B planes

#define TAUf 0.2f
#define NMS_EPS 1e-7f
#define DET_T 0.001f
#define NORMV (-7.6246189861593985f)   /* -log(2*K) */
#define LOGKV (6.9314718055994531f)    /* log(K) */

__constant__ float WR[6] = {1.0f, 1.0f/9.0f, 1.0f/25.0f, 1.0f/49.0f, 1.0f/81.0f, 1.0f/121.0f};

__device__ __forceinline__ int imin(int a,int b){return a<b?a:b;}
__device__ __forceinline__ int imax(int a,int b){return a>b?a:b;}

// float4-stage helper: load 4 floats at (gy, gxq..gxq+3), zero outside image
__device__ __forceinline__ float4 ld4z(const float* __restrict__ S, int gy, int gxq){
  float4 v;
  if(gy>=0&&gy<Hh&&gxq>=0&&gxq+3<Ww){
    v=*reinterpret_cast<const float4*>(&S[(size_t)gy*Ww+gxq]);
  }else{
    v.x=(gy>=0&&gy<Hh&&gxq>=0&&gxq<Ww)?S[(size_t)gy*Ww+gxq]:0.0f;
    v.y=(gy>=0&&gy<Hh&&gxq+1>=0&&gxq+1<Ww)?S[(size_t)gy*Ww+gxq+1]:0.0f;
    v.z=(gy>=0&&gy<Hh&&gxq+2>=0&&gxq+2<Ww)?S[(size_t)gy*Ww+gxq+2]:0.0f;
    v.w=(gy>=0&&gy<Hh&&gxq+3>=0&&gxq+3<Ww)?S[(size_t)gy*Ww+gxq+3]:0.0f;
  }
  return v;
}

// ---------------- fused: TWO FED diffusion steps (halo 4, float4 staging, MLP-unrolled) ----------------
__global__ __launch_bounds__(256) void fed2_step(const float* __restrict__ src, float* __restrict__ dst,
                const float* __restrict__ img1, const float* __restrict__ img2, int fromImgs){
  __shared__ float Lt[40][41];
  __shared__ float Gt[38][39];   // g1; reused for g2 (34x34 fits)
  __shared__ float Lp[36][37];   // L' with halo 2
  const int bx=blockIdx.x*32, by=blockIdx.y*32, b=blockIdx.z;
  const int gx0=bx-4, gy0=by-4;
  const float* S = fromImgs ? ((b<2?img1:img2)+(size_t)(b&1)*HWp) : (src+(size_t)b*HWp);
  float* D=dst+(size_t)b*HWp;
  const int t=threadIdx.y*32+threadIdx.x;
  const float k2=(float)(0.05*0.05);
  // stage 40x10 float4 (400 items) with both loads issued before stores
  {
    int i0=t, i1=t+256;
    int ly0=i0/10, q0=i0-ly0*10;
    float4 v0=ld4z(S, gy0+ly0, gx0+q0*4);
    float4 v1;
    int ly1=i1/10, q1=i1-ly1*10;
    if(i1<400) v1=ld4z(S, gy0+ly1, gx0+q1*4);
    int lx0=q0*4;
    Lt[ly0][lx0]=v0.x; Lt[ly0][lx0+1]=v0.y; Lt[ly0][lx0+2]=v0.z; Lt[ly0][lx0+3]=v0.w;
    if(i1<400){
      int lx1=q1*4;
      Lt[ly1][lx1]=v1.x; Lt[ly1][lx1+1]=v1.y; Lt[ly1][lx1+2]=v1.z; Lt[ly1][lx1+3]=v1.w;
    }
  }
  __syncthreads();
  for(int i=t;i<38*38;i+=256){
    int y=i/38+1, x=i-(i/38)*38+1;
    float sx=(-Lt[y-1][x-1]+Lt[y-1][x+1]-2.0f*Lt[y][x-1]+2.0f*Lt[y][x+1]-Lt[y+1][x-1]+Lt[y+1][x+1])*0.125f;
    float sy=(-Lt[y-1][x-1]-2.0f*Lt[y-1][x]-Lt[y-1][x+1]+Lt[y+1][x-1]+2.0f*Lt[y+1][x]+Lt[y+1][x+1])*0.125f;
    Gt[y-1][x-1]=1.0f/(1.0f+(sx*sx+sy*sy)/k2);
  }
  __syncthreads();
  for(int i=t;i<36*36;i+=256){
    int y=i/36+2, x=i-(i/36)*36+2;
    int gy=gy0+y, gx=gx0+x;
    float v=0.0f;
    if(gy>=0&&gy<Hh&&gx>=0&&gx<Ww){
      int yn=imax(gy-1,0)-gy0, ys=imin(gy+1,Hh-1)-gy0;
      int xw=imax(gx-1,0)-gx0, xe=imin(gx+1,Ww-1)-gx0;
      float Lc=Lt[y][x];
      float Ln=Lt[yn][x], Ls=Lt[ys][x], Lw=Lt[y][xw], Le=Lt[y][xe];
      float gc=Gt[y-1][x-1], gn=Gt[yn-1][x-1], gs=Gt[ys-1][x-1], gw=Gt[y-1][xw-1], ge=Gt[y-1][xe-1];
      float flux=0.5f*((gc+gn)*(Ln-Lc)+(gc+gs)*(Ls-Lc)+(gc+gw)*(Lw-Lc)+(gc+ge)*(Le-Lc));
      v=Lc+TAUf*flux;
    }
    Lp[y-2][x-2]=v;
  }
  __syncthreads();
  for(int i=t;i<34*34;i+=256){
    int y=i/34+1, x=i-(i/34)*34+1;
    float sx=(-Lp[y-1][x-1]+Lp[y-1][x+1]-2.0f*Lp[y][x-1]+2.0f*Lp[y][x+1]-Lp[y+1][x-1]+Lp[y+1][x+1])*0.125f;
    float sy=(-Lp[y-1][x-1]-2.0f*Lp[y-1][x]-Lp[y-1][x+1]+Lp[y+1][x-1]+2.0f*Lp[y+1][x]+Lp[y+1][x+1])*0.125f;
    Gt[y-1][x-1]=1.0f/(1.0f+(sx*sx+sy*sy)/k2);
  }
  __syncthreads();
  for(int i=t;i<32*8;i+=256){
    int oy=i>>3, ox4=(i&7)<<2;
    float vals[4];
    #pragma unroll
    for(int kq=0;kq<4;kq++){
      int ox=ox4+kq;
      int y=oy+2, x=ox+2;
      int gy=by+oy, gx=bx+ox;
      int yn=imax(gy-1,0)-(gy0+2), ys=imin(gy+1,Hh-1)-(gy0+2);
      int xw=imax(gx-1,0)-(gx0+2), xe=imin(gx+1,Ww-1)-(gx0+2);
      float Lc=Lp[y][x];
      float Ln=Lp[yn][x], Ls=Lp[ys][x], Lw=Lp[y][xw], Le=Lp[y][xe];
      float gc=Gt[y-1][x-1], gn=Gt[yn-1][x-1], gs=Gt[ys-1][x-1], gw=Gt[y-1][xw-1], ge=Gt[y-1][xe-1];
      float flux=0.5f*((gc+gn)*(Ln-Lc)+(gc+gs)*(Ls-Lc)+(gc+gw)*(Lw-Lc)+(gc+ge)*(Le-Lc));
      vals[kq]=Lc+TAUf*flux;
    }
    float4 o; o.x=vals[0]; o.y=vals[1]; o.z=vals[2]; o.w=vals[3];
    *reinterpret_cast<float4*>(&D[(size_t)(by+oy)*Ww+bx+ox4])=o;
  }
}

// ---------------- fused: one FED step + Hessian response (halo 4, float4 staging, MLP-unrolled) ----------------
__global__ __launch_bounds__(256) void fed_step_resp(const float* __restrict__ src, float* __restrict__ dstL,
                                                     float* __restrict__ resp, int first){
  __shared__ float Lt[40][41];
  __shared__ float Gt[38][39];
  __shared__ float Lp[36][37];
  const int bx=blockIdx.x*32, by=blockIdx.y*32, b=blockIdx.z;
  const int gx0=bx-4, gy0=by-4;
  const float* S=src+(size_t)b*HWp;
  float* DL=dstL+(size_t)b*HWp;
  float* R=resp+(size_t)b*HWp;
  const int t=threadIdx.y*32+threadIdx.x;
  const float k2=(float)(0.05*0.05);
  {
    int i0=t, i1=t+256;
    int ly0=i0/10, q0=i0-ly0*10;
    float4 v0=ld4z(S, gy0+ly0, gx0+q0*4);
    float4 v1;
    int ly1=i1/10, q1=i1-ly1*10;
    if(i1<400) v1=ld4z(S, gy0+ly1, gx0+q1*4);
    int lx0=q0*4;
    Lt[ly0][lx0]=v0.x; Lt[ly0][lx0+1]=v0.y; Lt[ly0][lx0+2]=v0.z; Lt[ly0][lx0+3]=v0.w;
    if(i1<400){
      int lx1=q1*4;
      Lt[ly1][lx1]=v1.x; Lt[ly1][lx1+1]=v1.y; Lt[ly1][lx1+2]=v1.z; Lt[ly1][lx1+3]=v1.w;
    }
  }
  __syncthreads();
  for(int i=t;i<38*38;i+=256){
    int y=i/38+1, x=i-(i/38)*38+1;
    float sx=(-Lt[y-1][x-1]+Lt[y-1][x+1]
              -2.0f*Lt[y][x-1]+2.0f*Lt[y][x+1]
              -Lt[y+1][x-1]+Lt[y+1][x+1])*0.125f;
    float sy=(-Lt[y-1][x-1]-2.0f*Lt[y-1][x]-Lt[y-1][x+1]
              +Lt[y+1][x-1]+2.0f*Lt[y+1][x]+Lt[y+1][x+1])*0.125f;
    Gt[y-1][x-1]=1.0f/(1.0f+(sx*sx+sy*sy)/k2);
  }
  __syncthreads();
  for(int i=t;i<36*36;i+=256){
    int y=i/36+2, x=i-(i/36)*36+2;
    int gy=gy0+y, gx=gx0+x;
    float v=0.0f;
    if(gy>=0&&gy<Hh&&gx>=0&&gx<Ww){
      int yn=imax(gy-1,0)-gy0, ys=imin(gy+1,Hh-1)-gy0;
      int xw=imax(gx-1,0)-gx0, xe=imin(gx+1,Ww-1)-gx0;
      float Lc=Lt[y][x];
      float Ln=Lt[yn][x], Ls=Lt[ys][x], Lw=Lt[y][xw], Le=Lt[y][xe];
      float gc=Gt[y-1][x-1], gn=Gt[yn-1][x-1], gs=Gt[ys-1][x-1], gw=Gt[y-1][xw-1], ge=Gt[y-1][xe-1];
      float flux=0.5f*((gc+gn)*(Ln-Lc)+(gc+gs)*(Ls-Lc)+(gc+gw)*(Lw-Lc)+(gc+ge)*(Le-Lc));
      v=Lc+TAUf*flux;
    }
    Lp[y-2][x-2]=v;
  }
  __syncthreads();
  for(int i=t;i<32*8;i+=256){
    int oy=i>>3, ox4=(i&7)<<2;
    float4 o;
    o.x=Lp[oy+2][ox4+2]; o.y=Lp[oy+2][ox4+3]; o.z=Lp[oy+2][ox4+4]; o.w=Lp[oy+2][ox4+5];
    *reinterpret_cast<float4*>(&DL[(size_t)(by+oy)*Ww+bx+ox4])=o;
  }
  for(int i=t;i<34*34;i+=256){
    int y=i/34+1, x=i-(i/34)*34+1;
    int gy=gy0+2+y, gx=gx0+2+x;
    float v=0.0f;
    if(gy>=0&&gy<Hh&&gx>=0&&gx<Ww){
      v=(-Lp[y-1][x-1]+Lp[y-1][x+1]
         -2.0f*Lp[y][x-1]+2.0f*Lp[y][x+1]
         -Lp[y+1][x-1]+Lp[y+1][x+1])*0.125f;
    }
    Gt[y-1][x-1]=v;
  }
  __syncthreads();
  for(int i=t;i<32*8;i+=256){
    int oy=i>>3, ox4=(i&7)<<2;
    float* rp=&R[(size_t)(by+oy)*Ww+bx+ox4];
    float4 rv;
    if(!first) rv=*reinterpret_cast<const float4*>(rp);
    float dets[4];
    #pragma unroll
    for(int kq=0;kq<4;kq++){
      int y=oy+2, x=ox4+kq+2;
      float Lxx=Lp[y][x-1]-2.0f*Lp[y][x]+Lp[y][x+1];
      float Lyy=Lp[y-1][x]-2.0f*Lp[y][x]+Lp[y+1][x];
      float Lxy=(-Gt[y-2][x-2]-2.0f*Gt[y-2][x-1]-Gt[y-2][x]
                 +Gt[y][x-2]+2.0f*Gt[y][x-1]+Gt[y][x])*0.125f;
      dets[kq]=Lxx*Lyy-Lxy*Lxy;
    }
    float4 o;
    o.x=first?fmaxf(dets[0],0.0f):fmaxf(rv.x,dets[0]);
    o.y=first?fmaxf(dets[1],0.0f):fmaxf(rv.y,dets[1]);
    o.z=first?fmaxf(dets[2],0.0f):fmaxf(rv.z,dets[2]);
    o.w=first?fmaxf(dets[3],0.0f):fmaxf(rv.w,dets[3]);
    *reinterpret_cast<float4*>(rp)=o;
  }
}

// ---------------- fused detect: threshold + 5x5 NMS (ballot bitmap) + sparse 7x7 NMS + compaction ----------------
__global__ __launch_bounds__(256) void detect_compact(const float* __restrict__ resp,
                                                      u64* __restrict__ lists,
                                                      int* __restrict__ cnt, int segbase){
  __shared__ float Tt[42][49];     // thresholded response; col base bx-8
  __shared__ u64 bm[38];
  __shared__ u64 keys[KEYCAP];
  __shared__ int lcnt, gbase;
  const int bx = blockIdx.x*32, by = blockIdx.y*32, b = blockIdx.z;
  const float* S = resp + (size_t)b*HWp;
  const int t = threadIdx.y*32 + threadIdx.x;
  if (t==0) lcnt=0;
  // stage 42x12 float4 (504 items): both loads issued before stores
  {
    int i0=t, i1=t+256;
    int ly0=i0/12, q0=i0-ly0*12;
    float4 v0=ld4z(S, by+ly0-5, bx-8+q0*4);
    float4 v1;
    int ly1=i1/12, q1=i1-ly1*12;
    if(i1<504) v1=ld4z(S, by+ly1-5, bx-8+q1*4);
    int lx0=q0*4;
    Tt[ly0][lx0  ]=(v0.x>DET_T)?v0.x:0.0f;
    Tt[ly0][lx0+1]=(v0.y>DET_T)?v0.y:0.0f;
    Tt[ly0][lx0+2]=(v0.z>DET_T)?v0.z:0.0f;
    Tt[ly0][lx0+3]=(v0.w>DET_T)?v0.w:0.0f;
    if(i1<504){
      int lx1=q1*4;
      Tt[ly1][lx1  ]=(v1.x>DET_T)?v1.x:0.0f;
      Tt[ly1][lx1+1]=(v1.y>DET_T)?v1.y:0.0f;
      Tt[ly1][lx1+2]=(v1.z>DET_T)?v1.z:0.0f;
      Tt[ly1][lx1+3]=(v1.w>DET_T)?v1.w:0.0f;
    }
  }
  __syncthreads();
  {
    int wave=t>>6, lane=t&63;
    for(int y=wave; y<38; y+=4){
      bool pred=false;
      if(lane<38){
        float m=0.0f;
        #pragma unroll
        for(int dy=0;dy<5;dy++)
          #pragma unroll
          for(int dx=0;dx<5;dx++)
            m=fmaxf(m,Tt[y+dy][lane+3+dx]);
        float c=Tt[y+2][lane+5];
        pred=(c>0.0f)&&(c>=m-NMS_EPS);
      }
      u64 mask=__ballot(pred);
      if(lane==0) bm[y]=mask;
    }
  }
  __syncthreads();
  const int seg=segbase+b;
  for (int r=0;r<4;++r){
    int oy=threadIdx.y + r*8, ox=threadIdx.x;
    bool pos=false; u64 key=0;
    if((bm[oy+3]>>(ox+3))&1ULL){
      float v=Tt[oy+5][ox+8];
      float m=0.0f;
      #pragma unroll
      for(int dy=0;dy<7;dy++){
        u32 chunk=(u32)((bm[oy+dy]>>ox)&0x7FULL);
        while(chunk){
          int j=__ffs(chunk)-1;
          m=fmaxf(m,Tt[oy+dy+2][ox+j+5]);
          chunk&=chunk-1;
        }
      }
      if(v>=m-NMS_EPS){
        u32 idx=(u32)((by+oy)*Ww+(bx+ox));
        key=((u64)__float_as_uint(v)<<32)|(u64)(0xFFFFFFFFu-idx);
        pos=true;
      }
    }
    u64 mask=__ballot(pos);
    if (mask){
      int lane=t&63;
      int leader=__ffsll((long long)mask)-1;
      int base=0;
      if (lane==leader) base=atomicAdd(&lcnt,__popcll(mask));
      base=__shfl(base,leader);
      if (pos){
        int rk=__popcll(mask & ((1ULL<<lane)-1ULL));
        if(base+rk<KEYCAP) keys[base+rk]=key;
      }
    }
  }
  __syncthreads();
  int n=imin(lcnt,KEYCAP);
  if (t==0 && n>0) gbase=atomicAdd(&cnt[seg*64], n);
  __syncthreads();
  for (int i=t;i<n;i+=256){
    int p=gbase+i;
    if (p<LISTCAP) lists[(size_t)seg*LISTCAP+p]=keys[i];
  }
}

// ---------------- topk stage A: 16-bit histogram (parallel) ----------------
__global__ __launch_bounds__(256) void topk_hist16(const u64* __restrict__ lists, const int* __restrict__ cnt,
                                                   u32* __restrict__ h16){
  int seg=blockIdx.y;
  int n=imin(cnt[seg*64],LISTCAP);
  const u64* L=lists+(size_t)seg*LISTCAP;
  u32* H=h16+(size_t)seg*65536;
  for(int i=blockIdx.x*256+threadIdx.x;i<n;i+=gridDim.x*256){
    u32 b=(u32)(L[i]>>48);
    atomicAdd(&H[b],1u);
  }
}

// ---------------- topk stage B: decide 16-bit prefix (1 block/seg) ----------------
__global__ __launch_bounds__(1024) void topk_decide16(const u32* __restrict__ h16, const int* __restrict__ cnt,
                                                      int* __restrict__ b16o, int* __restrict__ krem16,
                                                      int* __restrict__ takeAll, u64* __restrict__ Tf){
  int seg=blockIdx.x, tid=threadIdx.x;
  __shared__ u32 sc[1024];
  const u32* H=h16+(size_t)seg*65536;
  int n=imin(cnt[seg*64],LISTCAP);
  if(n<=Kk){
    if(tid==0){ takeAll[seg]=1; Tf[seg]=1ULL; b16o[seg]=-1; }
    return;
  }
  u32 csum=0;
  u32 hl[64];
  #pragma unroll 8
  for(int j=0;j<64;j++){ hl[j]=H[tid*64+j]; csum+=hl[j]; }
  sc[tid]=csum;
  __syncthreads();
  for(int off=1;off<1024;off<<=1){
    u32 v=(tid+off<1024)?sc[tid+off]:0u;
    __syncthreads();
    sc[tid]+=v;
    __syncthreads();
  }
  u32 nxt=(tid<1023)?sc[tid+1]:0u;
  if(sc[tid]>=(u32)Kk && nxt<(u32)Kk){
    u32 run=nxt;
    for(int j=63;j>=0;j--){
      u32 c=hl[j];
      run+=c;
      if(run>=(u32)Kk){
        b16o[seg]=tid*64+j;
        krem16[seg]=Kk-(int)(run-c);
        takeAll[seg]=0;
        break;
      }
    }
  }
}

// ---------------- topk stage C: compact keys matching 16-bit prefix (parallel) ----------------
__global__ __launch_bounds__(256) void topk_compact(const u64* __restrict__ lists, const int* __restrict__ cnt,
                                                    const int* __restrict__ b16o, const int* __restrict__ takeAll,
                                                    u64* __restrict__ candbuf, int* __restrict__ candcnt){
  int seg=blockIdx.y;
  if(takeAll[seg]) return;
  int n=imin(cnt[seg*64],LISTCAP);
  const u64* L=lists+(size_t)seg*LISTCAP;
  u32 b16=(u32)b16o[seg];
  for(int i0=blockIdx.x*256;i0<n;i0+=gridDim.x*256){
    int i=i0+threadIdx.x;
    bool sel=false; u64 k=0;
    if(i<n){ k=L[i]; sel=((u32)(k>>48)==b16); }
    u64 mask=__ballot(sel);
    if(mask){
      int lane=threadIdx.x&63;
      int leader=__ffsll((long long)mask)-1;
      int base=0;
      if(lane==leader) base=atomicAdd(&candcnt[seg*64],__popcll(mask));
      base=__shfl(base,leader);
      if(sel){
        int p=base+__popcll(mask & ((1ULL<<lane)-1ULL));
        if(p<CANDCAP) candbuf[(size_t)seg*CANDCAP+p]=k;
      }
    }
  }
}

// ---------------- topk stage D: remaining 6 radix rounds (LDS) -> threshold T ----------------
__global__ __launch_bounds__(1024) void topk_finish(const u64* __restrict__ lists, const int* __restrict__ cnt,
                                                    const u64* __restrict__ candbuf, const int* __restrict__ candcnt,
                                                    const int* __restrict__ b16o, const int* __restrict__ krem16,
                                                    const int* __restrict__ takeAll, u64* __restrict__ Tf){
  int seg=blockIdx.x, tid=threadIdx.x;
  if(takeAll[seg]) return;
  __shared__ u64 cands[CANDCAP];
  __shared__ u32 h[256], scan[256];
  __shared__ int bsel;
  int cc=candcnt[seg*64];
  u64 pfx=((u64)(u32)b16o[seg])<<48;
  int kr=krem16[seg];
  if(cc<=CANDCAP){
    for(int i=tid;i<cc;i+=1024) cands[i]=candbuf[(size_t)seg*CANDCAP+i];
    __syncthreads();
    for(int rd=0;rd<6;rd++){
      int shift=40-8*rd;
      u64 maskHi=~0ULL<<(shift+8);
      if(tid<256) h[tid]=0;
      __syncthreads();
      for(int i=tid;i<cc;i+=1024){
        u64 k=cands[i];
        if((k&maskHi)==pfx) atomicAdd(&h[(int)((k>>shift)&255ULL)],1u);
      }
      __syncthreads();
      if(tid<256) scan[tid]=h[tid];
      __syncthreads();
      for(int off=1;off<256;off<<=1){
        u32 v=0;
        if(tid<256 && tid+off<256) v=scan[tid+off];
        __syncthreads();
        if(tid<256) scan[tid]+=v;
        __syncthreads();
      }
      if(tid<256){
        bool ge=(scan[tid]>=(u32)kr);
        bool geN=(tid<255)?(scan[tid+1]>=(u32)kr):false;
        if(ge && !geN) bsel=tid;
      }
      __syncthreads();
      int b=bsel;
      int acc=(b<255)?(int)scan[b+1]:0;
      pfx |= ((u64)(u32)b)<<shift;
      kr -= acc;
      __syncthreads();
    }
  } else {
    int n=imin(cnt[seg*64],LISTCAP);
    const u64* L=lists+(size_t)seg*LISTCAP;
    for(int rd=0;rd<6;rd++){
      int shift=40-8*rd;
      u64 maskHi=~0ULL<<(shift+8);
      if(tid<256) h[tid]=0;
      __syncthreads();
      for(int i=tid;i<n;i+=1024){
        u64 k=L[i];
        if((k&maskHi)==pfx) atomicAdd(&h[(int)((k>>shift)&255ULL)],1u);
      }
      __syncthreads();
      if(tid<256) scan[tid]=h[tid];
      __syncthreads();
      for(int off=1;off<256;off<<=1){
        u32 v=0;
        if(tid<256 && tid+off<256) v=scan[tid+off];
        __syncthreads();
        if(tid<256) scan[tid]+=v;
        __syncthreads();
      }
      if(tid<256){
        bool ge=(scan[tid]>=(u32)kr);
        bool geN=(tid<255)?(scan[tid+1]>=(u32)kr):false;
        if(ge && !geN) bsel=tid;
      }
      __syncthreads();
      int b=bsel;
      int acc=(b<255)?(int)scan[b+1]:0;
      pfx |= ((u64)(u32)b)<<shift;
      kr -= acc;
      __syncthreads();
    }
  }
  if(tid==0) Tf[seg]=pfx;
}

// ---------------- topk stage E: gather keys >= T (parallel) ----------------
__global__ __launch_bounds__(256) void topk_gather(const u64* __restrict__ lists, const int* __restrict__ cnt,
                                                   const u64* __restrict__ Tf, u64* __restrict__ selbuf,
                                                   int* __restrict__ selcnt){
  int seg=blockIdx.y;
  int n=imin(cnt[seg*64],LISTCAP);
  u64 T=Tf[seg];
  const u64* L=lists+(size_t)seg*LISTCAP;
  for(int i0=blockIdx.x*256;i0<n;i0+=gridDim.x*256){
    int i=i0+threadIdx.x;
    bool sel=false; u64 k=0;
    if(i<n){ k=L[i]; sel=(k>=T); }
    u64 mask=__ballot(sel);
    if(mask){
      int lane=threadIdx.x&63;
      int leader=__ffsll((long long)mask)-1;
      int base=0;
      if(lane==leader) base=atomicAdd(&selcnt[seg*64],__popcll(mask));
      base=__shfl(base,leader);
      if(sel){
        int p=base+__popcll(mask & ((1ULL<<lane)-1ULL));
        if(p<Kk) selbuf[(size_t)seg*Kk+p]=k;
      }
    }
  }
}

// ---------------- sort 1024 keys desc, emit keypoint meta + k1/k2 ----------------
__global__ __launch_bounds__(1024) void finalize_kernel(const u64* __restrict__ selbuf, const int* __restrict__ selcnt,
                                int* __restrict__ kyi, int* __restrict__ kxi, float* __restrict__ kval,
                                float* __restrict__ outp){
  int seg=blockIdx.x, tid=threadIdx.x;
  __shared__ u64 a[1024];
  int n=selcnt[seg*64]; if(n>Kk)n=Kk;
  a[tid]=(tid<n)?selbuf[(size_t)seg*Kk+tid]:0ULL;
  __syncthreads();
  for(int k=2;k<=1024;k<<=1){
    for(int j=k>>1;j>0;j>>=1){
      int ixj=tid^j;
      if(ixj>tid){
        u64 x=a[tid], y=a[ixj];
        bool desc=((tid&k)==0);
        if(desc ? (x<y) : (x>y)){ a[tid]=y; a[ixj]=x; }
      }
      __syncthreads();
    }
  }
  u64 key=a[tid];
  bool val=(key!=0ULL);
  u32 idx=0xFFFFFFFFu-(u32)(key&0xFFFFFFFFULL);
  int y= val ? (int)(idx/Ww) : 0;
  int x= val ? (int)(idx%Ww) : 0;
  int mi=seg*Kk+tid;
  kyi[mi]=y; kxi[mi]=x; kval[mi]= val?1.0f:0.0f;
  int imi=seg>>1, bb=seg&1;
  float* ko=outp + (size_t)imi*(Bb*Kk*2) + ((size_t)bb*Kk+tid)*2;
  ko[0]= val ? (float)y : -1.0f;
  ko[1]= val ? (float)x : -1.0f;
}

// ---------------- BAD descriptor: MLP-unrolled patch stage + orientation + SAT + box sums ----------------
__global__ __launch_bounds__(256) void bad_kernel(const float* __restrict__ img1, const float* __restrict__ img2,
                           const float* __restrict__ offs, const float* __restrict__ thrv,
                           const int* __restrict__ rad,
                           const int* __restrict__ kyi, const int* __restrict__ kxi,
                           const float* __restrict__ kval,
                           float* __restrict__ d1, float* __restrict__ d2,
                           float* __restrict__ sq1, float* __restrict__ sq2){
  __shared__ float sat[PS+1][PS+2];
  __shared__ float sm[4], smx[4], smy[4];
  __shared__ float w15s[15];
  __shared__ float nsh, thsh;
  int seg=blockIdx.y, ki=blockIdx.x, p=threadIdx.x;
  const float* img=(seg<2?img1:img2)+(size_t)(seg&1)*HWp;
  int mi=seg*Kk+ki;
  int yci=kyi[mi], xci=kxi[mi];
  if(p==0){
    double w[15]; double Sw=0.0;
    for(int i=0;i<15;i++){ double c=(double)i-7.0; w[i]=exp(-(c*c)/(2.0*2.5*2.5)); Sw+=w[i]; }
    for(int i=0;i<15;i++) w15s[i]=(float)(w[i]/Sw);
  }
  for (int i=p;i<PS+1;i+=256){ sat[0][i]=0.0f; sat[i][0]=0.0f; }
  if (p==0) sat[0][PS]=0.0f;
  // vectorized + MLP-unrolled staging: 855 items (57 rows x 15 float4)
  {
    int x0=xci-PR;
    int xa=x0 & ~3;
    int d=x0-xa;             // 0..3
    int ids[4]={p, p+256, p+512, p+768};
    float4 vs[4];
    #pragma unroll
    for(int u=0;u<4;u++){
      if(ids[u]<PS*15){
        int ly=ids[u]/15, q=ids[u]-(ids[u]/15)*15;
        vs[u]=ld4z(img, yci-PR+ly, xa+q*4);
      }
    }
    #pragma unroll
    for(int u=0;u<4;u++){
      if(ids[u]<PS*15){
        int ly=ids[u]/15, q=ids[u]-(ids[u]/15)*15;
        #pragma unroll
        for(int k=0;k<4;k++){
          int lx=q*4+k-d;
          float vv=(k==0)?vs[u].x:((k==1)?vs[u].y:((k==2)?vs[u].z:vs[u].w));
          if(lx>=0&&lx<PS) sat[ly+1][lx+1]=vv;
        }
      }
    }
  }
  __syncthreads();
  {
    float ax=0.0f, ay=0.0f;
    if(p<225){
      int du=p/15-7, dv=p-(p/15)*15-7;
      int yy=yci+du, xx=xci+dv;
      if(yy>=0&&yy<Hh&&xx>=0&&xx<Ww){
        int ly=du+PR+1, lx=dv+PR+1;
        float p00=sat[ly-1][lx-1], p01=sat[ly-1][lx], p02=sat[ly-1][lx+1];
        float p10=sat[ly][lx-1],                       p12=sat[ly][lx+1];
        float p20=sat[ly+1][lx-1], p21=sat[ly+1][lx], p22=sat[ly+1][lx+1];
        float sx=(-p00+p02-2.0f*p10+2.0f*p12-p20+p22)*0.125f;
        float sy=(-p00-2.0f*p01-p02+p20+2.0f*p21+p22)*0.125f;
        float wgt=w15s[du+7]*w15s[dv+7];
        ax=wgt*sx; ay=wgt*sy;
      }
    }
    for(int o=32;o;o>>=1){ ax+=__shfl_down(ax,o); ay+=__shfl_down(ay,o); }
    if((p&63)==0){ smx[p>>6]=ax; smy[p>>6]=ay; }
    __syncthreads();
    if(p==0) thsh=atan2f(smy[0]+smy[1]+smy[2]+smy[3], smx[0]+smx[1]+smx[2]+smx[3]);
  }
  __syncthreads();
  if (p<PS){
    float run=0.0f;
    for(int x=1;x<=PS;x++){ run+=sat[p+1][x]; sat[p+1][x]=run; }
  }
  __syncthreads();
  if (p<PS){
    float run=0.0f;
    for(int y=1;y<=PS;y++){ run+=sat[y][p+1]; sat[y][p+1]=run; }
  }
  __syncthreads();
  float yc=(float)yci, xc=(float)xci;
  float th=thsh;
  float c=cosf(th), s=sinf(th);
  float ox1=offs[p*4+0], oy1=offs[p*4+1], ox2=offs[p*4+2], oy2=offs[p*4+3];
  int r=rad[p];
  float w=WR[r];
  float px1=xc+c*ox1-s*oy1, py1=yc+s*ox1+c*oy1;
  float px2=xc+c*ox2-s*oy2, py2=yc+s*ox2+c*oy2;
  auto boxl=[&](float px,float py,int r_)->float{
    float rx=rintf(px), ry=rintf(py);
    int xi=(int)fminf(fmaxf(rx,0.0f),(float)(Ww-1));
    int yi=(int)fminf(fmaxf(ry,0.0f),(float)(Hh-1));
    int lx=xi-(xci-PR), ly=yi-(yci-PR);
    int y2=ly+r_+1, y1=ly-r_, x2=lx+r_+1, x1=lx-r_;
    return sat[y2][x2]-sat[y1][x2]-sat[y2][x1]+sat[y1][x1];
  };
  float s1=boxl(px1,py1,r)*w;
  float s2=boxl(px2,py2,r)*w;
  float v=(s1-s2-thrv[p])*kval[mi];
  float t=v*v;
  for(int o=32;o;o>>=1) t+=__shfl_down(t,o);
  if((p&63)==0) sm[p>>6]=t;
  __syncthreads();
  if(p==0) nsh=sqrtf(sm[0]+sm[1]+sm[2]+sm[3]);
  __syncthreads();
  float dv=v/(nsh+1e-8f);
  float* dd=(seg<2?d1:d2);
  dd[((size_t)(seg&1)*Kk+ki)*Pp+p]=dv;
  float t2=dv*dv;
  for(int o=32;o;o>>=1) t2+=__shfl_down(t2,o);
  __syncthreads();
  if((p&63)==0) sm[p>>6]=t2;
  __syncthreads();
  if(p==0){ float* sq=(seg<2?sq1:sq2); sq[(size_t)(seg&1)*Kk+ki]=sm[0]+sm[1]+sm[2]+sm[3]; }
}

// ---------------- pairwise distance -> Z (padded stride, and transposed copy) ----------------
__global__ __launch_bounds__(256) void dist_kernel(const float* __restrict__ d1, const float* __restrict__ d2,
                            const float* __restrict__ sq1, const float* __restrict__ sq2,
                            float* __restrict__ Zm, float* __restrict__ Zt){
  int b=blockIdx.z;
  int i0=blockIdx.y*64, j0=blockIdx.x*64;
  int tid=threadIdx.x;
  int tx=tid&15, ty=tid>>4;
  __shared__ float Ast[64][68], Bst[64][68];
  const float* D1=d1+(size_t)b*Kk*Pp;
  const float* D2=d2+(size_t)b*Kk*Pp;
  float acc[4][4]={};
  for(int p0=0;p0<Pp;p0+=64){
    for(int i=tid;i<64*16;i+=256){
      int row=i>>4, c4=(i&15)<<2;
      float4 va=*reinterpret_cast<const float4*>(&D1[(size_t)(i0+row)*Pp+p0+c4]);
      float4 vb=*reinterpret_cast<const float4*>(&D2[(size_t)(j0+row)*Pp+p0+c4]);
      Ast[c4+0][row]=va.x; Ast[c4+1][row]=va.y; Ast[c4+2][row]=va.z; Ast[c4+3][row]=va.w;
      Bst[c4+0][row]=vb.x; Bst[c4+1][row]=vb.y; Bst[c4+2][row]=vb.z; Bst[c4+3][row]=vb.w;
    }
    __syncthreads();
    #pragma unroll 8
    for(int kk=0;kk<64;++kk){
      float4 av=*reinterpret_cast<const float4*>(&Ast[kk][ty*4]);
      float4 bv=*reinterpret_cast<const float4*>(&Bst[kk][tx*4]);
      acc[0][0]=fmaf(av.x,bv.x,acc[0][0]); acc[0][1]=fmaf(av.x,bv.y,acc[0][1]);
      acc[0][2]=fmaf(av.x,bv.z,acc[0][2]); acc[0][3]=fmaf(av.x,bv.w,acc[0][3]);
      acc[1][0]=fmaf(av.y,bv.x,acc[1][0]); acc[1][1]=fmaf(av.y,bv.y,acc[1][1]);
      acc[1][2]=fmaf(av.y,bv.z,acc[1][2]); acc[1][3]=fmaf(av.y,bv.w,acc[1][3]);
      acc[2][0]=fmaf(av.z,bv.x,acc[2][0]); acc[2][1]=fmaf(av.z,bv.y,acc[2][1]);
      acc[2][2]=fmaf(av.z,bv.z,acc[2][2]); acc[2][3]=fmaf(av.z,bv.w,acc[2][3]);
      acc[3][0]=fmaf(av.w,bv.x,acc[3][0]); acc[3][1]=fmaf(av.w,bv.y,acc[3][1]);
      acc[3][2]=fmaf(av.w,bv.z,acc[3][2]); acc[3][3]=fmaf(av.w,bv.w,acc[3][3]);
    }
    __syncthreads();
  }
  int gi=i0+ty*4, gj=j0+tx*4;
  float si[4], sj[4];
  #pragma unroll
  for(int i=0;i<4;i++){ si[i]=sq1[b*Kk+gi+i]; sj[i]=sq2[b*Kk+gj+i]; }
  #pragma unroll
  for(int i=0;i<4;i++){
    #pragma unroll
    for(int j=0;j<4;j++){
      float dd=si[i]+sj[j]-2.0f*acc[i][j];
      float dist=sqrtf(fmaxf(dd,0.0f)+1e-12f);
      Zm[(size_t)b*ZB+(size_t)(gi+i)*ZLD+(gj+j)]=-dist;
      Zt[(size_t)b*ZB+(size_t)(gj+j)*ZLD+(gi+i)]=-dist;
    }
  }
}

// ---------------- E = exp(Z) in fp16 with border/pad handling; tail threads init eu/ev ----------------
__global__ void expz_kernel(float* __restrict__ Zm, float* __restrict__ Zt,
                            __half* __restrict__ Em, __half* __restrict__ Et,
                            float* __restrict__ euv, float* __restrict__ evv){
  size_t q=(size_t)blockIdx.x*256+threadIdx.x;
  const size_t tot4=(size_t)Bb*ZB/4;
  if(q>=2*tot4){
    size_t r=q-2*tot4;
    if(r<(size_t)Bb*ZLD){
      int j=(int)(r%(size_t)ZLD);
      evv[r]=(j<KP1)?1.0f:0.0f;
      euv[r]=0.0f;
    }
    return;
  }
  float* src=(q<tot4)?Zm:Zt;
  __half* dst=(q<tot4)?Em:Et;
  size_t j=(q<tot4)?q:q-tot4;
  size_t jb=j%(ZB/4);
  int r=(int)(jb/(ZLD/4));
  int c0=(int)(jb%(ZLD/4))*4;
  float4 z=reinterpret_cast<const float4*>(src)[j];
  float zz[4]={z.x,z.y,z.z,z.w};
  float e[4];
  bool wb=false;
  #pragma unroll
  for(int k=0;k<4;k++){
    int c=c0+k;
    if(c>=KP1) e[k]=0.0f;
    else if(r==Kk||c==Kk){ zz[k]=1.0f; e[k]=expf(1.0f); wb=true; }
    else e[k]=expf(zz[k]);
  }
  if(wb){
    float4 zo; zo.x=zz[0]; zo.y=zz[1]; zo.z=zz[2]; zo.w=zz[3];
    reinterpret_cast<float4*>(src)[j]=zo;
  }
  __half2 a=__floats2half2_rn(e[0],e[1]);
  __half2 b2=__floats2half2_rn(e[2],e[3]);
  reinterpret_cast<__half2*>(dst)[2*j]=a;
  reinterpret_cast<__half2*>(dst)[2*j+1]=b2;
}

// ---------------- Sinkhorn half-iteration as fp16 GEMV: eu = elm / (E @ ev); u = lm - log(s) ----------------
struct H4{ __half2 a, b; };
__global__ __launch_bounds__(256) void sink_gemv(const __half* __restrict__ E,
        const float* __restrict__ evin, float* __restrict__ euout, float* __restrict__ uout){
  int row=blockIdx.x*4+(threadIdx.x>>6);
  if(row>=Bb*KP1) return;
  int b=row/KP1, i=row-b*KP1;
  int lane=threadIdx.x&63;
  const H4* e4=reinterpret_cast<const H4*>(E+((size_t)b*KP1+i)*ZLD);
  const float4* v4=reinterpret_cast<const float4*>(evin+(size_t)b*ZLD);
  float s=0.0f;
  for(int j=lane;j<ZLD/4;j+=64){
    H4 e=e4[j]; float4 v=v4[j];
    float2 ea=__half22float2(e.a), eb=__half22float2(e.b);
    s=fmaf(ea.x,v.x,s); s=fmaf(ea.y,v.y,s);
    s=fmaf(eb.x,v.z,s); s=fmaf(eb.y,v.w,s);
  }
  for(int o=32;o;o>>=1) s+=__shfl_down(s,o);
  if(lane==0){
    float lm,elm;
    if(i<Kk){ lm=NORMV; elm=4.8828125e-4f; }
    else    { lm=LOGKV+NORMV; elm=0.5f; }
    euout[(size_t)b*ZLD+i]=elm/s;
    uout [(size_t)b*ZLD+i]=lm-logf(s);
  }
}

// ---------------- final probs = exp(Z+u+v-norm) ----------------
__global__ void probs_kernel(const float* __restrict__ Zm, const float* __restrict__ uu,
                             const float* __restrict__ vv, float* __restrict__ outp){
  size_t i=(size_t)blockIdx.x*256+threadIdx.x;
  const size_t tot=(size_t)Bb*KP1*KP1;
  if(i>=tot) return;
  size_t b=i/((size_t)KP1*KP1);
  size_t rem=i-b*(size_t)KP1*KP1;
  int rr=(int)(rem/KP1), cc=(int)(rem-(size_t)(rem/KP1)*KP1);
  outp[i]=expf(Zm[b*ZB+(size_t)rr*ZLD+cc]+uu[b*ZLD+rr]+vv[b*ZLD+cc]-NORMV);
}

extern "C" void kernel_launch(void* const* d_in, const int* in_sizes, int n_in,
                              void* d_out, int out_size, void* d_ws, size_t ws_size,
                              hipStream_t stream) {
  (void)in_sizes; (void)n_in; (void)out_size;
  const float* img1=(const float*)d_in[0];
  const float* img2=(const float*)d_in[1];
  const float* offs=(const float*)d_in[2];
  const float* thrv=(const float*)d_in[3];
  const int*   rad =(const int*)d_in[4];
  float* out=(float*)d_out;

  const bool batched = ws_size >= ((size_t)80<<20);
  const int NP = batched ? 4 : 2;
  const size_t PB = HWp*(size_t)NP*4;

  char* wp=(char*)d_ws;
  auto carve=[&](size_t bytes)->char*{ char* p=wp; wp += (bytes+255)&~(size_t)255; return p; };
  float* r0  =(float*)carve(PB);               // L ping / Zm
  float* r1  =(float*)carve(PB);               // L pong / Zt
  float* resp=(float*)carve(PB);               // resp / Em,Et (fp16)
  u64*  lists=(u64*)carve((size_t)NSEG*LISTCAP*8);
  char* stateblk = carve(8192);
  int* cnt     =(int*)(stateblk);              // [seg*64]
  int* selcnt  =(int*)(stateblk+1024);         // [seg*64]
  int* b16o    =(int*)(stateblk+2048);         // [seg]
  int* krem16  =(int*)(stateblk+2112);
  int* takeAll =(int*)(stateblk+2176);
  u64* Tf      =(u64*)(stateblk+2240);
  int* candcnt =(int*)(stateblk+4096);         // [seg*64]
  u32* h16     =(u32*)carve((size_t)NSEG*65536*4);   // 1MB, contiguous with stateblk
  u64* candbuf =(u64*)carve((size_t)NSEG*CANDCAP*8); // 256KB
  u64* selbuf  =(u64*)carve((size_t)NSEG*Kk*8);
  int* kyi     =(int*)carve((size_t)NSEG*Kk*4);
  int* kxi     =(int*)carve((size_t)NSEG*Kk*4);
  float* kval  =(float*)carve((size_t)NSEG*Kk*4);
  float* d1    =(float*)carve((size_t)Bb*Kk*Pp*4);
  float* d2    =(float*)carve((size_t)Bb*Kk*Pp*4);
  float* sq1   =(float*)carve((size_t)Bb*Kk*4);
  float* sq2   =(float*)carve((size_t)Bb*Kk*4);
  float* uvec  =(float*)carve((size_t)Bb*ZLD*4);
  float* vvec  =(float*)carve((size_t)Bb*ZLD*4);
  float* euvec =(float*)carve((size_t)Bb*ZLD*4);
  float* evvec =(float*)carve((size_t)Bb*ZLD*4);

  const size_t EBYTES = ((size_t)Bb*ZB*2 + 255)&~(size_t)255;
  __half* Em=(__half*)resp;
  __half* Et=(__half*)((char*)resp + EBYTES);

  hipMemsetAsync(stateblk, 0, 8192 + (size_t)NSEG*65536*4, stream);

  dim3 TB(32,8);
  if (batched){
    dim3 TG(Ww/32, Hh/32, 4);
    fed2_step    <<<TG,TB,0,stream>>>(r0, r1, img1, img2, 1);   // steps 1-2 (direct from images)
    fed_step_resp<<<TG,TB,0,stream>>>(r1, r0, resp, 1);         // step 3 + response
    fed2_step    <<<TG,TB,0,stream>>>(r0, r1, img1, img2, 0);   // steps 4-5
    fed_step_resp<<<TG,TB,0,stream>>>(r1, r0, resp, 0);         // step 6 + response
    fed2_step    <<<TG,TB,0,stream>>>(r0, r1, img1, img2, 0);   // steps 7-8
    fed_step_resp<<<TG,TB,0,stream>>>(r1, r0, resp, 0);         // step 9 + response
    detect_compact<<<TG,TB,0,stream>>>(resp, lists, cnt, 0);
  } else {
    dim3 TG(Ww/32, Hh/32, Bb);
    for(int im=0; im<2; ++im){
      const float* srcimg = (im==0)? img1 : img2;
      hipMemcpyAsync(r0, srcimg, PLn*4, hipMemcpyDeviceToDevice, stream);
      fed2_step    <<<TG,TB,0,stream>>>(r0, r1, img1, img2, 0);
      fed_step_resp<<<TG,TB,0,stream>>>(r1, r0, resp, 1);
      fed2_step    <<<TG,TB,0,stream>>>(r0, r1, img1, img2, 0);
      fed_step_resp<<<TG,TB,0,stream>>>(r1, r0, resp, 0);
      fed2_step    <<<TG,TB,0,stream>>>(r0, r1, img1, img2, 0);
      fed_step_resp<<<TG,TB,0,stream>>>(r1, r0, resp, 0);
      detect_compact<<<TG,TB,0,stream>>>(resp, lists, cnt, im*2);
    }
  }

  topk_hist16 <<<dim3(32,NSEG),dim3(256),0,stream>>>(lists, cnt, h16);
  topk_decide16<<<dim3(NSEG),dim3(1024),0,stream>>>(h16, cnt, b16o, krem16, takeAll, Tf);
  topk_compact<<<dim3(32,NSEG),dim3(256),0,stream>>>(lists, cnt, b16o, takeAll, candbuf, candcnt);
  topk_finish <<<dim3(NSEG),dim3(1024),0,stream>>>(lists, cnt, candbuf, candcnt, b16o, krem16, takeAll, Tf);
  topk_gather <<<dim3(32,NSEG),dim3(256),0,stream>>>(lists, cnt, Tf, selbuf, selcnt);
  finalize_kernel<<<NSEG,1024,0,stream>>>(selbuf, selcnt, kyi, kxi, kval, out);
  bad_kernel<<<dim3(Kk,NSEG),dim3(256),0,stream>>>(img1, img2, offs, thrv, rad,
                                                   kyi, kxi, kval, d1, d2, sq1, sq2);

  float* Zm=r0; float* Zt=r1;
  dist_kernel<<<dim3(16,16,Bb),dim3(256),0,stream>>>(d1,d2,sq1,sq2,Zm,Zt);
  {
    size_t tot4=(size_t)Bb*ZB/4;
    size_t totThreads=2*tot4 + (size_t)Bb*ZLD;
    expz_kernel<<<dim3((u32)((totThreads+255)/256)),dim3(256),0,stream>>>(Zm,Zt,Em,Et,euvec,evvec);
  }
  for(int it=0; it<20; ++it){
    sink_gemv<<<dim3((Bb*KP1+3)/4),dim3(256),0,stream>>>(Em, evvec, euvec, uvec);
    sink_gemv<<<dim3((Bb*KP1+3)/4),dim3(256),0,stream>>>(Et, euvec, evvec, vvec);
  }
  size_t tot=(size_t)Bb*KP1*KP1;
  probs_kernel<<<dim3((u32)((tot+255)/256)),dim3(256),0,stream>>>(Zm, uvec, vvec, out + (size_t)2*Bb*Kk*2);
}

// Round 18
// 532.151 us; speedup vs baseline: 1.0086x; 1.0086x over previous
//
#include <hip/hip_runtime.h>
#include <hip/hip_fp16.h>
#include <math.h>

typedef unsigned long long u64;
typedef unsigned int u32;

#define Hh 960
#define Ww 1280
#define Bb 2
#define Kk 1024
#define Pp 256
#define KP1 1025
#define NSEG 4
#define LISTCAP 131072
#define PR 28
#define PS 57
#define ZLD 1040                         /* padded Z row stride (16B-aligned) */
#define CANDCAP 8192
#define KEYCAP 256
static const size_t ZB = (size_t)KP1*ZLD;  // per-batch Z floats

static const size_t HWp = (size_t)Hh * Ww;   // one plane
static const size_t PLn = HWp * Bb;          // B planes

#define TAUf 0.2f
#define NMS_EPS 1e-7f
#define DET_T 0.001f
#define NORMV (-7.6246189861593985f)   /* -log(2*K) */
#define LOGKV (6.9314718055994531f)    /* log(K) */

__constant__ float WR[6] = {1.0f, 1.0f/9.0f, 1.0f/25.0f, 1.0f/49.0f, 1.0f/81.0f, 1.0f/121.0f};

__device__ __forceinline__ int imin(int a,int b){return a<b?a:b;}
__device__ __forceinline__ int imax(int a,int b){return a>b?a:b;}

// float4-stage helper: load 4 floats at (gy, gxq..gxq+3), zero outside image
__device__ __forceinline__ float4 ld4z(const float* __restrict__ S, int gy, int gxq){
  float4 v;
  if(gy>=0&&gy<Hh&&gxq>=0&&gxq+3<Ww){
    v=*reinterpret_cast<const float4*>(&S[(size_t)gy*Ww+gxq]);
  }else{
    v.x=(gy>=0&&gy<Hh&&gxq>=0&&gxq<Ww)?S[(size_t)gy*Ww+gxq]:0.0f;
    v.y=(gy>=0&&gy<Hh&&gxq+1>=0&&gxq+1<Ww)?S[(size_t)gy*Ww+gxq+1]:0.0f;
    v.z=(gy>=0&&gy<Hh&&gxq+2>=0&&gxq+2<Ww)?S[(size_t)gy*Ww+gxq+2]:0.0f;
    v.w=(gy>=0&&gy<Hh&&gxq+3>=0&&gxq+3<Ww)?S[(size_t)gy*Ww+gxq+3]:0.0f;
  }
  return v;
}

// ---------------- fused: TWO FED diffusion steps (halo 4, float4 staging) ----------------
__global__ __launch_bounds__(256) void fed2_step(const float* __restrict__ src, float* __restrict__ dst,
                const float* __restrict__ img1, const float* __restrict__ img2, int fromImgs){
  __shared__ float Lt[40][41];
  __shared__ float Gt[38][39];   // g1; reused for g2 (34x34 fits)
  __shared__ float Lp[36][37];   // L' with halo 2
  const int bx=blockIdx.x*32, by=blockIdx.y*32, b=blockIdx.z;
  const int gx0=bx-4, gy0=by-4;
  const float* S = fromImgs ? ((b<2?img1:img2)+(size_t)(b&1)*HWp) : (src+(size_t)b*HWp);
  float* D=dst+(size_t)b*HWp;
  const int t=threadIdx.y*32+threadIdx.x;
  const float k2=(float)(0.05*0.05);
  {
    int i0=t, i1=t+256;
    int ly0=i0/10, q0=i0-ly0*10;
    float4 v0=ld4z(S, gy0+ly0, gx0+q0*4);
    float4 v1;
    int ly1=i1/10, q1=i1-ly1*10;
    if(i1<400) v1=ld4z(S, gy0+ly1, gx0+q1*4);
    int lx0=q0*4;
    Lt[ly0][lx0]=v0.x; Lt[ly0][lx0+1]=v0.y; Lt[ly0][lx0+2]=v0.z; Lt[ly0][lx0+3]=v0.w;
    if(i1<400){
      int lx1=q1*4;
      Lt[ly1][lx1]=v1.x; Lt[ly1][lx1+1]=v1.y; Lt[ly1][lx1+2]=v1.z; Lt[ly1][lx1+3]=v1.w;
    }
  }
  __syncthreads();
  for(int i=t;i<38*38;i+=256){
    int y=i/38+1, x=i-(i/38)*38+1;
    float sx=(-Lt[y-1][x-1]+Lt[y-1][x+1]-2.0f*Lt[y][x-1]+2.0f*Lt[y][x+1]-Lt[y+1][x-1]+Lt[y+1][x+1])*0.125f;
    float sy=(-Lt[y-1][x-1]-2.0f*Lt[y-1][x]-Lt[y-1][x+1]+Lt[y+1][x-1]+2.0f*Lt[y+1][x]+Lt[y+1][x+1])*0.125f;
    Gt[y-1][x-1]=1.0f/(1.0f+(sx*sx+sy*sy)/k2);
  }
  __syncthreads();
  for(int i=t;i<36*36;i+=256){
    int y=i/36+2, x=i-(i/36)*36+2;
    int gy=gy0+y, gx=gx0+x;
    float v=0.0f;
    if(gy>=0&&gy<Hh&&gx>=0&&gx<Ww){
      int yn=imax(gy-1,0)-gy0, ys=imin(gy+1,Hh-1)-gy0;
      int xw=imax(gx-1,0)-gx0, xe=imin(gx+1,Ww-1)-gx0;
      float Lc=Lt[y][x];
      float Ln=Lt[yn][x], Ls=Lt[ys][x], Lw=Lt[y][xw], Le=Lt[y][xe];
      float gc=Gt[y-1][x-1], gn=Gt[yn-1][x-1], gs=Gt[ys-1][x-1], gw=Gt[y-1][xw-1], ge=Gt[y-1][xe-1];
      float flux=0.5f*((gc+gn)*(Ln-Lc)+(gc+gs)*(Ls-Lc)+(gc+gw)*(Lw-Lc)+(gc+ge)*(Le-Lc));
      v=Lc+TAUf*flux;
    }
    Lp[y-2][x-2]=v;
  }
  __syncthreads();
  for(int i=t;i<34*34;i+=256){
    int y=i/34+1, x=i-(i/34)*34+1;
    float sx=(-Lp[y-1][x-1]+Lp[y-1][x+1]-2.0f*Lp[y][x-1]+2.0f*Lp[y][x+1]-Lp[y+1][x-1]+Lp[y+1][x+1])*0.125f;
    float sy=(-Lp[y-1][x-1]-2.0f*Lp[y-1][x]-Lp[y-1][x+1]+Lp[y+1][x-1]+2.0f*Lp[y+1][x]+Lp[y+1][x+1])*0.125f;
    Gt[y-1][x-1]=1.0f/(1.0f+(sx*sx+sy*sy)/k2);
  }
  __syncthreads();
  for(int i=t;i<32*8;i+=256){
    int oy=i>>3, ox4=(i&7)<<2;
    float vals[4];
    #pragma unroll
    for(int kq=0;kq<4;kq++){
      int ox=ox4+kq;
      int y=oy+2, x=ox+2;
      int gy=by+oy, gx=bx+ox;
      int yn=imax(gy-1,0)-(gy0+2), ys=imin(gy+1,Hh-1)-(gy0+2);
      int xw=imax(gx-1,0)-(gx0+2), xe=imin(gx+1,Ww-1)-(gx0+2);
      float Lc=Lp[y][x];
      float Ln=Lp[yn][x], Ls=Lp[ys][x], Lw=Lp[y][xw], Le=Lp[y][xe];
      float gc=Gt[y-1][x-1], gn=Gt[yn-1][x-1], gs=Gt[ys-1][x-1], gw=Gt[y-1][xw-1], ge=Gt[y-1][xe-1];
      float flux=0.5f*((gc+gn)*(Ln-Lc)+(gc+gs)*(Ls-Lc)+(gc+gw)*(Lw-Lc)+(gc+ge)*(Le-Lc));
      vals[kq]=Lc+TAUf*flux;
    }
    float4 o; o.x=vals[0]; o.y=vals[1]; o.z=vals[2]; o.w=vals[3];
    *reinterpret_cast<float4*>(&D[(size_t)(by+oy)*Ww+bx+ox4])=o;
  }
}

// ---------------- fused: one FED step + Hessian response (halo 4, float4 staging) ----------------
__global__ __launch_bounds__(256) void fed_step_resp(const float* __restrict__ src, float* __restrict__ dstL,
                                                     float* __restrict__ resp, int first){
  __shared__ float Lt[40][41];
  __shared__ float Gt[38][39];
  __shared__ float Lp[36][37];
  const int bx=blockIdx.x*32, by=blockIdx.y*32, b=blockIdx.z;
  const int gx0=bx-4, gy0=by-4;
  const float* S=src+(size_t)b*HWp;
  float* DL=dstL+(size_t)b*HWp;
  float* R=resp+(size_t)b*HWp;
  const int t=threadIdx.y*32+threadIdx.x;
  const float k2=(float)(0.05*0.05);
  {
    int i0=t, i1=t+256;
    int ly0=i0/10, q0=i0-ly0*10;
    float4 v0=ld4z(S, gy0+ly0, gx0+q0*4);
    float4 v1;
    int ly1=i1/10, q1=i1-ly1*10;
    if(i1<400) v1=ld4z(S, gy0+ly1, gx0+q1*4);
    int lx0=q0*4;
    Lt[ly0][lx0]=v0.x; Lt[ly0][lx0+1]=v0.y; Lt[ly0][lx0+2]=v0.z; Lt[ly0][lx0+3]=v0.w;
    if(i1<400){
      int lx1=q1*4;
      Lt[ly1][lx1]=v1.x; Lt[ly1][lx1+1]=v1.y; Lt[ly1][lx1+2]=v1.z; Lt[ly1][lx1+3]=v1.w;
    }
  }
  __syncthreads();
  for(int i=t;i<38*38;i+=256){
    int y=i/38+1, x=i-(i/38)*38+1;
    float sx=(-Lt[y-1][x-1]+Lt[y-1][x+1]
              -2.0f*Lt[y][x-1]+2.0f*Lt[y][x+1]
              -Lt[y+1][x-1]+Lt[y+1][x+1])*0.125f;
    float sy=(-Lt[y-1][x-1]-2.0f*Lt[y-1][x]-Lt[y-1][x+1]
              +Lt[y+1][x-1]+2.0f*Lt[y+1][x]+Lt[y+1][x+1])*0.125f;
    Gt[y-1][x-1]=1.0f/(1.0f+(sx*sx+sy*sy)/k2);
  }
  __syncthreads();
  for(int i=t;i<36*36;i+=256){
    int y=i/36+2, x=i-(i/36)*36+2;
    int gy=gy0+y, gx=gx0+x;
    float v=0.0f;
    if(gy>=0&&gy<Hh&&gx>=0&&gx<Ww){
      int yn=imax(gy-1,0)-gy0, ys=imin(gy+1,Hh-1)-gy0;
      int xw=imax(gx-1,0)-gx0, xe=imin(gx+1,Ww-1)-gx0;
      float Lc=Lt[y][x];
      float Ln=Lt[yn][x], Ls=Lt[ys][x], Lw=Lt[y][xw], Le=Lt[y][xe];
      float gc=Gt[y-1][x-1], gn=Gt[yn-1][x-1], gs=Gt[ys-1][x-1], gw=Gt[y-1][xw-1], ge=Gt[y-1][xe-1];
      float flux=0.5f*((gc+gn)*(Ln-Lc)+(gc+gs)*(Ls-Lc)+(gc+gw)*(Lw-Lc)+(gc+ge)*(Le-Lc));
      v=Lc+TAUf*flux;
    }
    Lp[y-2][x-2]=v;
  }
  __syncthreads();
  for(int i=t;i<32*8;i+=256){
    int oy=i>>3, ox4=(i&7)<<2;
    float4 o;
    o.x=Lp[oy+2][ox4+2]; o.y=Lp[oy+2][ox4+3]; o.z=Lp[oy+2][ox4+4]; o.w=Lp[oy+2][ox4+5];
    *reinterpret_cast<float4*>(&DL[(size_t)(by+oy)*Ww+bx+ox4])=o;
  }
  for(int i=t;i<34*34;i+=256){
    int y=i/34+1, x=i-(i/34)*34+1;
    int gy=gy0+2+y, gx=gx0+2+x;
    float v=0.0f;
    if(gy>=0&&gy<Hh&&gx>=0&&gx<Ww){
      v=(-Lp[y-1][x-1]+Lp[y-1][x+1]
         -2.0f*Lp[y][x-1]+2.0f*Lp[y][x+1]
         -Lp[y+1][x-1]+Lp[y+1][x+1])*0.125f;
    }
    Gt[y-1][x-1]=v;
  }
  __syncthreads();
  for(int i=t;i<32*8;i+=256){
    int oy=i>>3, ox4=(i&7)<<2;
    float* rp=&R[(size_t)(by+oy)*Ww+bx+ox4];
    float4 rv;
    if(!first) rv=*reinterpret_cast<const float4*>(rp);
    float dets[4];
    #pragma unroll
    for(int kq=0;kq<4;kq++){
      int y=oy+2, x=ox4+kq+2;
      float Lxx=Lp[y][x-1]-2.0f*Lp[y][x]+Lp[y][x+1];
      float Lyy=Lp[y-1][x]-2.0f*Lp[y][x]+Lp[y+1][x];
      float Lxy=(-Gt[y-2][x-2]-2.0f*Gt[y-2][x-1]-Gt[y-2][x]
                 +Gt[y][x-2]+2.0f*Gt[y][x-1]+Gt[y][x])*0.125f;
      dets[kq]=Lxx*Lyy-Lxy*Lxy;
    }
    float4 o;
    o.x=first?fmaxf(dets[0],0.0f):fmaxf(rv.x,dets[0]);
    o.y=first?fmaxf(dets[1],0.0f):fmaxf(rv.y,dets[1]);
    o.z=first?fmaxf(dets[2],0.0f):fmaxf(rv.z,dets[2]);
    o.w=first?fmaxf(dets[3],0.0f):fmaxf(rv.w,dets[3]);
    *reinterpret_cast<float4*>(rp)=o;
  }
}

// ---------------- fused detect: threshold + SEPARABLE 5x5 NMS (H5 pass + ballot bitmap) + sparse 7x7 NMS ----------------
__global__ __launch_bounds__(256) void detect_compact(const float* __restrict__ resp,
                                                      u64* __restrict__ lists,
                                                      int* __restrict__ cnt, int segbase){
  __shared__ float Tt[42][49];     // thresholded response; col base bx-8
  __shared__ float H5[42][40];     // horizontal 5-max at Ss-x coords 0..37, all 42 Tt rows
  __shared__ u64 bm[38];
  __shared__ u64 keys[KEYCAP];
  __shared__ int lcnt, gbase;
  const int bx = blockIdx.x*32, by = blockIdx.y*32, b = blockIdx.z;
  const float* S = resp + (size_t)b*HWp;
  const int t = threadIdx.y*32 + threadIdx.x;
  if (t==0) lcnt=0;
  // stage 42x12 float4 (504 items)
  {
    int i0=t, i1=t+256;
    int ly0=i0/12, q0=i0-ly0*12;
    float4 v0=ld4z(S, by+ly0-5, bx-8+q0*4);
    float4 v1;
    int ly1=i1/12, q1=i1-ly1*12;
    if(i1<504) v1=ld4z(S, by+ly1-5, bx-8+q1*4);
    int lx0=q0*4;
    Tt[ly0][lx0  ]=(v0.x>DET_T)?v0.x:0.0f;
    Tt[ly0][lx0+1]=(v0.y>DET_T)?v0.y:0.0f;
    Tt[ly0][lx0+2]=(v0.z>DET_T)?v0.z:0.0f;
    Tt[ly0][lx0+3]=(v0.w>DET_T)?v0.w:0.0f;
    if(i1<504){
      int lx1=q1*4;
      Tt[ly1][lx1  ]=(v1.x>DET_T)?v1.x:0.0f;
      Tt[ly1][lx1+1]=(v1.y>DET_T)?v1.y:0.0f;
      Tt[ly1][lx1+2]=(v1.z>DET_T)?v1.z:0.0f;
      Tt[ly1][lx1+3]=(v1.w>DET_T)?v1.w:0.0f;
    }
  }
  __syncthreads();
  // Phase A: horizontal 5-max. H5[y][x] = max(Tt[y][x+3..x+7]) for x in 0..37, y in 0..41
  for(int i=t;i<42*38;i+=256){
    int y=i/38, x=i-(i/38)*38;
    float m=Tt[y][x+3];
    m=fmaxf(m,Tt[y][x+4]); m=fmaxf(m,Tt[y][x+5]);
    m=fmaxf(m,Tt[y][x+6]); m=fmaxf(m,Tt[y][x+7]);
    H5[y][x]=m;
  }
  __syncthreads();
  // Phase B: vertical 5-max + center compare -> row bitmaps (wave=rows stride 4, lane=col)
  {
    int wave=t>>6, lane=t&63;
    for(int y=wave; y<38; y+=4){
      bool pred=false;
      if(lane<38){
        float m=H5[y][lane];
        m=fmaxf(m,H5[y+1][lane]); m=fmaxf(m,H5[y+2][lane]);
        m=fmaxf(m,H5[y+3][lane]); m=fmaxf(m,H5[y+4][lane]);
        float c=Tt[y+2][lane+5];
        pred=(c>0.0f)&&(c>=m-NMS_EPS);
      }
      u64 mask=__ballot(pred);
      if(lane==0) bm[y]=mask;
    }
  }
  __syncthreads();
  const int seg=segbase+b;
  for (int r=0;r<4;++r){
    int oy=threadIdx.y + r*8, ox=threadIdx.x;
    bool pos=false; u64 key=0;
    if((bm[oy+3]>>(ox+3))&1ULL){
      float v=Tt[oy+5][ox+8];
      float m=0.0f;
      #pragma unroll
      for(int dy=0;dy<7;dy++){
        u32 chunk=(u32)((bm[oy+dy]>>ox)&0x7FULL);
        while(chunk){
          int j=__ffs(chunk)-1;
          m=fmaxf(m,Tt[oy+dy+2][ox+j+5]);
          chunk&=chunk-1;
        }
      }
      if(v>=m-NMS_EPS){
        u32 idx=(u32)((by+oy)*Ww+(bx+ox));
        key=((u64)__float_as_uint(v)<<32)|(u64)(0xFFFFFFFFu-idx);
        pos=true;
      }
    }
    u64 mask=__ballot(pos);
    if (mask){
      int lane=t&63;
      int leader=__ffsll((long long)mask)-1;
      int base=0;
      if (lane==leader) base=atomicAdd(&lcnt,__popcll(mask));
      base=__shfl(base,leader);
      if (pos){
        int rk=__popcll(mask & ((1ULL<<lane)-1ULL));
        if(base+rk<KEYCAP) keys[base+rk]=key;
      }
    }
  }
  __syncthreads();
  int n=imin(lcnt,KEYCAP);
  if (t==0 && n>0) gbase=atomicAdd(&cnt[seg*64], n);
  __syncthreads();
  for (int i=t;i<n;i+=256){
    int p=gbase+i;
    if (p<LISTCAP) lists[(size_t)seg*LISTCAP+p]=keys[i];
  }
}

// ---------------- topk stage A: 16-bit histogram (parallel) ----------------
__global__ __launch_bounds__(256) void topk_hist16(const u64* __restrict__ lists, const int* __restrict__ cnt,
                                                   u32* __restrict__ h16){
  int seg=blockIdx.y;
  int n=imin(cnt[seg*64],LISTCAP);
  const u64* L=lists+(size_t)seg*LISTCAP;
  u32* H=h16+(size_t)seg*65536;
  for(int i=blockIdx.x*256+threadIdx.x;i<n;i+=gridDim.x*256){
    u32 b=(u32)(L[i]>>48);
    atomicAdd(&H[b],1u);
  }
}

// ---------------- topk stage B: decide 16-bit prefix (1 block/seg) ----------------
__global__ __launch_bounds__(1024) void topk_decide16(const u32* __restrict__ h16, const int* __restrict__ cnt,
                                                      int* __restrict__ b16o, int* __restrict__ krem16,
                                                      int* __restrict__ takeAll, u64* __restrict__ Tf){
  int seg=blockIdx.x, tid=threadIdx.x;
  __shared__ u32 sc[1024];
  const u32* H=h16+(size_t)seg*65536;
  int n=imin(cnt[seg*64],LISTCAP);
  if(n<=Kk){
    if(tid==0){ takeAll[seg]=1; Tf[seg]=1ULL; b16o[seg]=-1; }
    return;
  }
  u32 csum=0;
  u32 hl[64];
  #pragma unroll 8
  for(int j=0;j<64;j++){ hl[j]=H[tid*64+j]; csum+=hl[j]; }
  sc[tid]=csum;
  __syncthreads();
  for(int off=1;off<1024;off<<=1){
    u32 v=(tid+off<1024)?sc[tid+off]:0u;
    __syncthreads();
    sc[tid]+=v;
    __syncthreads();
  }
  u32 nxt=(tid<1023)?sc[tid+1]:0u;
  if(sc[tid]>=(u32)Kk && nxt<(u32)Kk){
    u32 run=nxt;
    for(int j=63;j>=0;j--){
      u32 c=hl[j];
      run+=c;
      if(run>=(u32)Kk){
        b16o[seg]=tid*64+j;
        krem16[seg]=Kk-(int)(run-c);
        takeAll[seg]=0;
        break;
      }
    }
  }
}

// ---------------- topk stage C: compact keys matching 16-bit prefix (parallel) ----------------
__global__ __launch_bounds__(256) void topk_compact(const u64* __restrict__ lists, const int* __restrict__ cnt,
                                                    const int* __restrict__ b16o, const int* __restrict__ takeAll,
                                                    u64* __restrict__ candbuf, int* __restrict__ candcnt){
  int seg=blockIdx.y;
  if(takeAll[seg]) return;
  int n=imin(cnt[seg*64],LISTCAP);
  const u64* L=lists+(size_t)seg*LISTCAP;
  u32 b16=(u32)b16o[seg];
  for(int i0=blockIdx.x*256;i0<n;i0+=gridDim.x*256){
    int i=i0+threadIdx.x;
    bool sel=false; u64 k=0;
    if(i<n){ k=L[i]; sel=((u32)(k>>48)==b16); }
    u64 mask=__ballot(sel);
    if(mask){
      int lane=threadIdx.x&63;
      int leader=__ffsll((long long)mask)-1;
      int base=0;
      if(lane==leader) base=atomicAdd(&candcnt[seg*64],__popcll(mask));
      base=__shfl(base,leader);
      if(sel){
        int p=base+__popcll(mask & ((1ULL<<lane)-1ULL));
        if(p<CANDCAP) candbuf[(size_t)seg*CANDCAP+p]=k;
      }
    }
  }
}

// ---------------- topk stage D: remaining 6 radix rounds (LDS) -> threshold T ----------------
__global__ __launch_bounds__(1024) void topk_finish(const u64* __restrict__ lists, const int* __restrict__ cnt,
                                                    const u64* __restrict__ candbuf, const int* __restrict__ candcnt,
                                                    const int* __restrict__ b16o, const int* __restrict__ krem16,
                                                    const int* __restrict__ takeAll, u64* __restrict__ Tf){
  int seg=blockIdx.x, tid=threadIdx.x;
  if(takeAll[seg]) return;
  __shared__ u64 cands[CANDCAP];
  __shared__ u32 h[256], scan[256];
  __shared__ int bsel;
  int cc=candcnt[seg*64];
  u64 pfx=((u64)(u32)b16o[seg])<<48;
  int kr=krem16[seg];
  if(cc<=CANDCAP){
    for(int i=tid;i<cc;i+=1024) cands[i]=candbuf[(size_t)seg*CANDCAP+i];
    __syncthreads();
    for(int rd=0;rd<6;rd++){
      int shift=40-8*rd;
      u64 maskHi=~0ULL<<(shift+8);
      if(tid<256) h[tid]=0;
      __syncthreads();
      for(int i=tid;i<cc;i+=1024){
        u64 k=cands[i];
        if((k&maskHi)==pfx) atomicAdd(&h[(int)((k>>shift)&255ULL)],1u);
      }
      __syncthreads();
      if(tid<256) scan[tid]=h[tid];
      __syncthreads();
      for(int off=1;off<256;off<<=1){
        u32 v=0;
        if(tid<256 && tid+off<256) v=scan[tid+off];
        __syncthreads();
        if(tid<256) scan[tid]+=v;
        __syncthreads();
      }
      if(tid<256){
        bool ge=(scan[tid]>=(u32)kr);
        bool geN=(tid<255)?(scan[tid+1]>=(u32)kr):false;
        if(ge && !geN) bsel=tid;
      }
      __syncthreads();
      int b=bsel;
      int acc=(b<255)?(int)scan[b+1]:0;
      pfx |= ((u64)(u32)b)<<shift;
      kr -= acc;
      __syncthreads();
    }
  } else {
    int n=imin(cnt[seg*64],LISTCAP);
    const u64* L=lists+(size_t)seg*LISTCAP;
    for(int rd=0;rd<6;rd++){
      int shift=40-8*rd;
      u64 maskHi=~0ULL<<(shift+8);
      if(tid<256) h[tid]=0;
      __syncthreads();
      for(int i=tid;i<n;i+=1024){
        u64 k=L[i];
        if((k&maskHi)==pfx) atomicAdd(&h[(int)((k>>shift)&255ULL)],1u);
      }
      __syncthreads();
      if(tid<256) scan[tid]=h[tid];
      __syncthreads();
      for(int off=1;off<256;off<<=1){
        u32 v=0;
        if(tid<256 && tid+off<256) v=scan[tid+off];
        __syncthreads();
        if(tid<256) scan[tid]+=v;
        __syncthreads();
      }
      if(tid<256){
        bool ge=(scan[tid]>=(u32)kr);
        bool geN=(tid<255)?(scan[tid+1]>=(u32)kr):false;
        if(ge && !geN) bsel=tid;
      }
      __syncthreads();
      int b=bsel;
      int acc=(b<255)?(int)scan[b+1]:0;
      pfx |= ((u64)(u32)b)<<shift;
      kr -= acc;
      __syncthreads();
    }
  }
  if(tid==0) Tf[seg]=pfx;
}

// ---------------- topk stage E: gather keys >= T (parallel) ----------------
__global__ __launch_bounds__(256) void topk_gather(const u64* __restrict__ lists, const int* __restrict__ cnt,
                                                   const u64* __restrict__ Tf, u64* __restrict__ selbuf,
                                                   int* __restrict__ selcnt){
  int seg=blockIdx.y;
  int n=imin(cnt[seg*64],LISTCAP);
  u64 T=Tf[seg];
  const u64* L=lists+(size_t)seg*LISTCAP;
  for(int i0=blockIdx.x*256;i0<n;i0+=gridDim.x*256){
    int i=i0+threadIdx.x;
    bool sel=false; u64 k=0;
    if(i<n){ k=L[i]; sel=(k>=T); }
    u64 mask=__ballot(sel);
    if(mask){
      int lane=threadIdx.x&63;
      int leader=__ffsll((long long)mask)-1;
      int base=0;
      if(lane==leader) base=atomicAdd(&selcnt[seg*64],__popcll(mask));
      base=__shfl(base,leader);
      if(sel){
        int p=base+__popcll(mask & ((1ULL<<lane)-1ULL));
        if(p<Kk) selbuf[(size_t)seg*Kk+p]=k;
      }
    }
  }
}

// ---------------- sort 1024 keys desc, emit keypoint meta + k1/k2 ----------------
__global__ __launch_bounds__(1024) void finalize_kernel(const u64* __restrict__ selbuf, const int* __restrict__ selcnt,
                                int* __restrict__ kyi, int* __restrict__ kxi, float* __restrict__ kval,
                                float* __restrict__ outp){
  int seg=blockIdx.x, tid=threadIdx.x;
  __shared__ u64 a[1024];
  int n=selcnt[seg*64]; if(n>Kk)n=Kk;
  a[tid]=(tid<n)?selbuf[(size_t)seg*Kk+tid]:0ULL;
  __syncthreads();
  for(int k=2;k<=1024;k<<=1){
    for(int j=k>>1;j>0;j>>=1){
      int ixj=tid^j;
      if(ixj>tid){
        u64 x=a[tid], y=a[ixj];
        bool desc=((tid&k)==0);
        if(desc ? (x<y) : (x>y)){ a[tid]=y; a[ixj]=x; }
      }
      __syncthreads();
    }
  }
  u64 key=a[tid];
  bool val=(key!=0ULL);
  u32 idx=0xFFFFFFFFu-(u32)(key&0xFFFFFFFFULL);
  int y= val ? (int)(idx/Ww) : 0;
  int x= val ? (int)(idx%Ww) : 0;
  int mi=seg*Kk+tid;
  kyi[mi]=y; kxi[mi]=x; kval[mi]= val?1.0f:0.0f;
  int imi=seg>>1, bb=seg&1;
  float* ko=outp + (size_t)imi*(Bb*Kk*2) + ((size_t)bb*Kk+tid)*2;
  ko[0]= val ? (float)y : -1.0f;
  ko[1]= val ? (float)x : -1.0f;
}

// ---------------- BAD descriptor: MLP-unrolled patch stage + orientation + SAT + box sums ----------------
__global__ __launch_bounds__(256) void bad_kernel(const float* __restrict__ img1, const float* __restrict__ img2,
                           const float* __restrict__ offs, const float* __restrict__ thrv,
                           const int* __restrict__ rad,
                           const int* __restrict__ kyi, const int* __restrict__ kxi,
                           const float* __restrict__ kval,
                           float* __restrict__ d1, float* __restrict__ d2,
                           float* __restrict__ sq1, float* __restrict__ sq2){
  __shared__ float sat[PS+1][PS+2];
  __shared__ float sm[4], smx[4], smy[4];
  __shared__ float w15s[15];
  __shared__ float nsh, thsh;
  int seg=blockIdx.y, ki=blockIdx.x, p=threadIdx.x;
  const float* img=(seg<2?img1:img2)+(size_t)(seg&1)*HWp;
  int mi=seg*Kk+ki;
  int yci=kyi[mi], xci=kxi[mi];
  if(p==0){
    double w[15]; double Sw=0.0;
    for(int i=0;i<15;i++){ double c=(double)i-7.0; w[i]=exp(-(c*c)/(2.0*2.5*2.5)); Sw+=w[i]; }
    for(int i=0;i<15;i++) w15s[i]=(float)(w[i]/Sw);
  }
  for (int i=p;i<PS+1;i+=256){ sat[0][i]=0.0f; sat[i][0]=0.0f; }
  if (p==0) sat[0][PS]=0.0f;
  {
    int x0=xci-PR;
    int xa=x0 & ~3;
    int d=x0-xa;             // 0..3
    int ids[4]={p, p+256, p+512, p+768};
    float4 vs[4];
    #pragma unroll
    for(int u=0;u<4;u++){
      if(ids[u]<PS*15){
        int ly=ids[u]/15, q=ids[u]-(ids[u]/15)*15;
        vs[u]=ld4z(img, yci-PR+ly, xa+q*4);
      }
    }
    #pragma unroll
    for(int u=0;u<4;u++){
      if(ids[u]<PS*15){
        int ly=ids[u]/15, q=ids[u]-(ids[u]/15)*15;
        #pragma unroll
        for(int k=0;k<4;k++){
          int lx=q*4+k-d;
          float vv=(k==0)?vs[u].x:((k==1)?vs[u].y:((k==2)?vs[u].z:vs[u].w));
          if(lx>=0&&lx<PS) sat[ly+1][lx+1]=vv;
        }
      }
    }
  }
  __syncthreads();
  {
    float ax=0.0f, ay=0.0f;
    if(p<225){
      int du=p/15-7, dv=p-(p/15)*15-7;
      int yy=yci+du, xx=xci+dv;
      if(yy>=0&&yy<Hh&&xx>=0&&xx<Ww){
        int ly=du+PR+1, lx=dv+PR+1;
        float p00=sat[ly-1][lx-1], p01=sat[ly-1][lx], p02=sat[ly-1][lx+1];
        float p10=sat[ly][lx-1],                       p12=sat[ly][lx+1];
        float p20=sat[ly+1][lx-1], p21=sat[ly+1][lx], p22=sat[ly+1][lx+1];
        float sx=(-p00+p02-2.0f*p10+2.0f*p12-p20+p22)*0.125f;
        float sy=(-p00-2.0f*p01-p02+p20+2.0f*p21+p22)*0.125f;
        float wgt=w15s[du+7]*w15s[dv+7];
        ax=wgt*sx; ay=wgt*sy;
      }
    }
    for(int o=32;o;o>>=1){ ax+=__shfl_down(ax,o); ay+=__shfl_down(ay,o); }
    if((p&63)==0){ smx[p>>6]=ax; smy[p>>6]=ay; }
    __syncthreads();
    if(p==0) thsh=atan2f(smy[0]+smy[1]+smy[2]+smy[3], smx[0]+smx[1]+smx[2]+smx[3]);
  }
  __syncthreads();
  if (p<PS){
    float run=0.0f;
    for(int x=1;x<=PS;x++){ run+=sat[p+1][x]; sat[p+1][x]=run; }
  }
  __syncthreads();
  if (p<PS){
    float run=0.0f;
    for(int y=1;y<=PS;y++){ run+=sat[y][p+1]; sat[y][p+1]=run; }
  }
  __syncthreads();
  float yc=(float)yci, xc=(float)xci;
  float th=thsh;
  float c=cosf(th), s=sinf(th);
  float ox1=offs[p*4+0], oy1=offs[p*4+1], ox2=offs[p*4+2], oy2=offs[p*4+3];
  int r=rad[p];
  float w=WR[r];
  float px1=xc+c*ox1-s*oy1, py1=yc+s*ox1+c*oy1;
  float px2=xc+c*ox2-s*oy2, py2=yc+s*ox2+c*oy2;
  auto boxl=[&](float px,float py,int r_)->float{
    float rx=rintf(px), ry=rintf(py);
    int xi=(int)fminf(fmaxf(rx,0.0f),(float)(Ww-1));
    int yi=(int)fminf(fmaxf(ry,0.0f),(float)(Hh-1));
    int lx=xi-(xci-PR), ly=yi-(yci-PR);
    int y2=ly+r_+1, y1=ly-r_, x2=lx+r_+1, x1=lx-r_;
    return sat[y2][x2]-sat[y1][x2]-sat[y2][x1]+sat[y1][x1];
  };
  float s1=boxl(px1,py1,r)*w;
  float s2=boxl(px2,py2,r)*w;
  float v=(s1-s2-thrv[p])*kval[mi];
  float t=v*v;
  for(int o=32;o;o>>=1) t+=__shfl_down(t,o);
  if((p&63)==0) sm[p>>6]=t;
  __syncthreads();
  if(p==0) nsh=sqrtf(sm[0]+sm[1]+sm[2]+sm[3]);
  __syncthreads();
  float dv=v/(nsh+1e-8f);
  float* dd=(seg<2?d1:d2);
  dd[((size_t)(seg&1)*Kk+ki)*Pp+p]=dv;
  float t2=dv*dv;
  for(int o=32;o;o>>=1) t2+=__shfl_down(t2,o);
  __syncthreads();
  if((p&63)==0) sm[p>>6]=t2;
  __syncthreads();
  if(p==0){ float* sq=(seg<2?sq1:sq2); sq[(size_t)(seg&1)*Kk+ki]=sm[0]+sm[1]+sm[2]+sm[3]; }
}

// ---------------- pairwise distance -> Z (padded stride, and transposed copy) ----------------
__global__ __launch_bounds__(256) void dist_kernel(const float* __restrict__ d1, const float* __restrict__ d2,
                            const float* __restrict__ sq1, const float* __restrict__ sq2,
                            float* __restrict__ Zm, float* __restrict__ Zt){
  int b=blockIdx.z;
  int i0=blockIdx.y*64, j0=blockIdx.x*64;
  int tid=threadIdx.x;
  int tx=tid&15, ty=tid>>4;
  __shared__ float Ast[64][68], Bst[64][68];
  const float* D1=d1+(size_t)b*Kk*Pp;
  const float* D2=d2+(size_t)b*Kk*Pp;
  float acc[4][4]={};
  for(int p0=0;p0<Pp;p0+=64){
    for(int i=tid;i<64*16;i+=256){
      int row=i>>4, c4=(i&15)<<2;
      float4 va=*reinterpret_cast<const float4*>(&D1[(size_t)(i0+row)*Pp+p0+c4]);
      float4 vb=*reinterpret_cast<const float4*>(&D2[(size_t)(j0+row)*Pp+p0+c4]);
      Ast[c4+0][row]=va.x; Ast[c4+1][row]=va.y; Ast[c4+2][row]=va.z; Ast[c4+3][row]=va.w;
      Bst[c4+0][row]=vb.x; Bst[c4+1][row]=vb.y; Bst[c4+2][row]=vb.z; Bst[c4+3][row]=vb.w;
    }
    __syncthreads();
    #pragma unroll 8
    for(int kk=0;kk<64;++kk){
      float4 av=*reinterpret_cast<const float4*>(&Ast[kk][ty*4]);
      float4 bv=*reinterpret_cast<const float4*>(&Bst[kk][tx*4]);
      acc[0][0]=fmaf(av.x,bv.x,acc[0][0]); acc[0][1]=fmaf(av.x,bv.y,acc[0][1]);
      acc[0][2]=fmaf(av.x,bv.z,acc[0][2]); acc[0][3]=fmaf(av.x,bv.w,acc[0][3]);
      acc[1][0]=fmaf(av.y,bv.x,acc[1][0]); acc[1][1]=fmaf(av.y,bv.y,acc[1][1]);
      acc[1][2]=fmaf(av.y,bv.z,acc[1][2]); acc[1][3]=fmaf(av.y,bv.w,acc[1][3]);
      acc[2][0]=fmaf(av.z,bv.x,acc[2][0]); acc[2][1]=fmaf(av.z,bv.y,acc[2][1]);
      acc[2][2]=fmaf(av.z,bv.z,acc[2][2]); acc[2][3]=fmaf(av.z,bv.w,acc[2][3]);
      acc[3][0]=fmaf(av.w,bv.x,acc[3][0]); acc[3][1]=fmaf(av.w,bv.y,acc[3][1]);
      acc[3][2]=fmaf(av.w,bv.z,acc[3][2]); acc[3][3]=fmaf(av.w,bv.w,acc[3][3]);
    }
    __syncthreads();
  }
  int gi=i0+ty*4, gj=j0+tx*4;
  float si[4], sj[4];
  #pragma unroll
  for(int i=0;i<4;i++){ si[i]=sq1[b*Kk+gi+i]; sj[i]=sq2[b*Kk+gj+i]; }
  #pragma unroll
  for(int i=0;i<4;i++){
    #pragma unroll
    for(int j=0;j<4;j++){
      float dd=si[i]+sj[j]-2.0f*acc[i][j];
      float dist=sqrtf(fmaxf(dd,0.0f)+1e-12f);
      Zm[(size_t)b*ZB+(size_t)(gi+i)*ZLD+(gj+j)]=-dist;
      Zt[(size_t)b*ZB+(size_t)(gj+j)*ZLD+(gi+i)]=-dist;
    }
  }
}

// ---------------- E = exp(Z) in fp16 with border/pad handling; tail threads init eu/ev ----------------
__global__ void expz_kernel(float* __restrict__ Zm, float* __restrict__ Zt,
                            __half* __restrict__ Em, __half* __restrict__ Et,
                            float* __restrict__ euv, float* __restrict__ evv){
  size_t q=(size_t)blockIdx.x*256+threadIdx.x;
  const size_t tot4=(size_t)Bb*ZB/4;
  if(q>=2*tot4){
    size_t r=q-2*tot4;
    if(r<(size_t)Bb*ZLD){
      int j=(int)(r%(size_t)ZLD);
      evv[r]=(j<KP1)?1.0f:0.0f;
      euv[r]=0.0f;
    }
    return;
  }
  float* src=(q<tot4)?Zm:Zt;
  __half* dst=(q<tot4)?Em:Et;
  size_t j=(q<tot4)?q:q-tot4;
  size_t jb=j%(ZB/4);
  int r=(int)(jb/(ZLD/4));
  int c0=(int)(jb%(ZLD/4))*4;
  float4 z=reinterpret_cast<const float4*>(src)[j];
  float zz[4]={z.x,z.y,z.z,z.w};
  float e[4];
  bool wb=false;
  #pragma unroll
  for(int k=0;k<4;k++){
    int c=c0+k;
    if(c>=KP1) e[k]=0.0f;
    else if(r==Kk||c==Kk){ zz[k]=1.0f; e[k]=expf(1.0f); wb=true; }
    else e[k]=expf(zz[k]);
  }
  if(wb){
    float4 zo; zo.x=zz[0]; zo.y=zz[1]; zo.z=zz[2]; zo.w=zz[3];
    reinterpret_cast<float4*>(src)[j]=zo;
  }
  __half2 a=__floats2half2_rn(e[0],e[1]);
  __half2 b2=__floats2half2_rn(e[2],e[3]);
  reinterpret_cast<__half2*>(dst)[2*j]=a;
  reinterpret_cast<__half2*>(dst)[2*j+1]=b2;
}

// ---------------- Sinkhorn half-iteration as fp16 GEMV: eu = elm / (E @ ev); u = lm - log(s) ----------------
struct H4{ __half2 a, b; };
__global__ __launch_bounds__(256) void sink_gemv(const __half* __restrict__ E,
        const float* __restrict__ evin, float* __restrict__ euout, float* __restrict__ uout){
  int row=blockIdx.x*4+(threadIdx.x>>6);
  if(row>=Bb*KP1) return;
  int b=row/KP1, i=row-b*KP1;
  int lane=threadIdx.x&63;
  const H4* e4=reinterpret_cast<const H4*>(E+((size_t)b*KP1+i)*ZLD);
  const float4* v4=reinterpret_cast<const float4*>(evin+(size_t)b*ZLD);
  float s=0.0f;
  for(int j=lane;j<ZLD/4;j+=64){
    H4 e=e4[j]; float4 v=v4[j];
    float2 ea=__half22float2(e.a), eb=__half22float2(e.b);
    s=fmaf(ea.x,v.x,s); s=fmaf(ea.y,v.y,s);
    s=fmaf(eb.x,v.z,s); s=fmaf(eb.y,v.w,s);
  }
  for(int o=32;o;o>>=1) s+=__shfl_down(s,o);
  if(lane==0){
    float lm,elm;
    if(i<Kk){ lm=NORMV; elm=4.8828125e-4f; }
    else    { lm=LOGKV+NORMV; elm=0.5f; }
    euout[(size_t)b*ZLD+i]=elm/s;
    uout [(size_t)b*ZLD+i]=lm-logf(s);
  }
}

// ---------------- final probs = exp(Z+u+v-norm) ----------------
__global__ void probs_kernel(const float* __restrict__ Zm, const float* __restrict__ uu,
                             const float* __restrict__ vv, float* __restrict__ outp){
  size_t i=(size_t)blockIdx.x*256+threadIdx.x;
  const size_t tot=(size_t)Bb*KP1*KP1;
  if(i>=tot) return;
  size_t b=i/((size_t)KP1*KP1);
  size_t rem=i-b*(size_t)KP1*KP1;
  int rr=(int)(rem/KP1), cc=(int)(rem-(size_t)(rem/KP1)*KP1);
  outp[i]=expf(Zm[b*ZB+(size_t)rr*ZLD+cc]+uu[b*ZLD+rr]+vv[b*ZLD+cc]-NORMV);
}

extern "C" void kernel_launch(void* const* d_in, const int* in_sizes, int n_in,
                              void* d_out, int out_size, void* d_ws, size_t ws_size,
                              hipStream_t stream) {
  (void)in_sizes; (void)n_in; (void)out_size;
  const float* img1=(const float*)d_in[0];
  const float* img2=(const float*)d_in[1];
  const float* offs=(const float*)d_in[2];
  const float* thrv=(const float*)d_in[3];
  const int*   rad =(const int*)d_in[4];
  float* out=(float*)d_out;

  const bool batched = ws_size >= ((size_t)80<<20);
  const int NP = batched ? 4 : 2;
  const size_t PB = HWp*(size_t)NP*4;

  char* wp=(char*)d_ws;
  auto carve=[&](size_t bytes)->char*{ char* p=wp; wp += (bytes+255)&~(size_t)255; return p; };
  float* r0  =(float*)carve(PB);               // L ping / Zm
  float* r1  =(float*)carve(PB);               // L pong / Zt
  float* resp=(float*)carve(PB);               // resp / Em,Et (fp16)
  u64*  lists=(u64*)carve((size_t)NSEG*LISTCAP*8);
  char* stateblk = carve(8192);
  int* cnt     =(int*)(stateblk);              // [seg*64]
  int* selcnt  =(int*)(stateblk+1024);         // [seg*64]
  int* b16o    =(int*)(stateblk+2048);         // [seg]
  int* krem16  =(int*)(stateblk+2112);
  int* takeAll =(int*)(stateblk+2176);
  u64* Tf      =(u64*)(stateblk+2240);
  int* candcnt =(int*)(stateblk+4096);         // [seg*64]
  u32* h16     =(u32*)carve((size_t)NSEG*65536*4);   // 1MB, contiguous with stateblk
  u64* candbuf =(u64*)carve((size_t)NSEG*CANDCAP*8); // 256KB
  u64* selbuf  =(u64*)carve((size_t)NSEG*Kk*8);
  int* kyi     =(int*)carve((size_t)NSEG*Kk*4);
  int* kxi     =(int*)carve((size_t)NSEG*Kk*4);
  float* kval  =(float*)carve((size_t)NSEG*Kk*4);
  float* d1    =(float*)carve((size_t)Bb*Kk*Pp*4);
  float* d2    =(float*)carve((size_t)Bb*Kk*Pp*4);
  float* sq1   =(float*)carve((size_t)Bb*Kk*4);
  float* sq2   =(float*)carve((size_t)Bb*Kk*4);
  float* uvec  =(float*)carve((size_t)Bb*ZLD*4);
  float* vvec  =(float*)carve((size_t)Bb*ZLD*4);
  float* euvec =(float*)carve((size_t)Bb*ZLD*4);
  float* evvec =(float*)carve((size_t)Bb*ZLD*4);

  const size_t EBYTES = ((size_t)Bb*ZB*2 + 255)&~(size_t)255;
  __half* Em=(__half*)resp;
  __half* Et=(__half*)((char*)resp + EBYTES);

  hipMemsetAsync(stateblk, 0, 8192 + (size_t)NSEG*65536*4, stream);

  dim3 TB(32,8);
  if (batched){
    dim3 TG(Ww/32, Hh/32, 4);
    fed2_step    <<<TG,TB,0,stream>>>(r0, r1, img1, img2, 1);   // steps 1-2 (direct from images)
    fed_step_resp<<<TG,TB,0,stream>>>(r1, r0, resp, 1);         // step 3 + response
    fed2_step    <<<TG,TB,0,stream>>>(r0, r1, img1, img2, 0);   // steps 4-5
    fed_step_resp<<<TG,TB,0,stream>>>(r1, r0, resp, 0);         // step 6 + response
    fed2_step    <<<TG,TB,0,stream>>>(r0, r1, img1, img2, 0);   // steps 7-8
    fed_step_resp<<<TG,TB,0,stream>>>(r1, r0, resp, 0);         // step 9 + response
    detect_compact<<<TG,TB,0,stream>>>(resp, lists, cnt, 0);
  } else {
    dim3 TG(Ww/32, Hh/32, Bb);
    for(int im=0; im<2; ++im){
      const float* srcimg = (im==0)? img1 : img2;
      hipMemcpyAsync(r0, srcimg, PLn*4, hipMemcpyDeviceToDevice, stream);
      fed2_step    <<<TG,TB,0,stream>>>(r0, r1, img1, img2, 0);
      fed_step_resp<<<TG,TB,0,stream>>>(r1, r0, resp, 1);
      fed2_step    <<<TG,TB,0,stream>>>(r0, r1, img1, img2, 0);
      fed_step_resp<<<TG,TB,0,stream>>>(r1, r0, resp, 0);
      fed2_step    <<<TG,TB,0,stream>>>(r0, r1, img1, img2, 0);
      fed_step_resp<<<TG,TB,0,stream>>>(r1, r0, resp, 0);
      detect_compact<<<TG,TB,0,stream>>>(resp, lists, cnt, im*2);
    }
  }

  topk_hist16 <<<dim3(32,NSEG),dim3(256),0,stream>>>(lists, cnt, h16);
  topk_decide16<<<dim3(NSEG),dim3(1024),0,stream>>>(h16, cnt, b16o, krem16, takeAll, Tf);
  topk_compact<<<dim3(32,NSEG),dim3(256),0,stream>>>(lists, cnt, b16o, takeAll, candbuf, candcnt);
  topk_finish <<<dim3(NSEG),dim3(1024),0,stream>>>(lists, cnt, candbuf, candcnt, b16o, krem16, takeAll, Tf);
  topk_gather <<<dim3(32,NSEG),dim3(256),0,stream>>>(lists, cnt, Tf, selbuf, selcnt);
  finalize_kernel<<<NSEG,1024,0,stream>>>(selbuf, selcnt, kyi, kxi, kval, out);
  bad_kernel<<<dim3(Kk,NSEG),dim3(256),0,stream>>>(img1, img2, offs, thrv, rad,
                                                   kyi, kxi, kval, d1, d2, sq1, sq2);

  float* Zm=r0; float* Zt=r1;
  dist_kernel<<<dim3(16,16,Bb),dim3(256),0,stream>>>(d1,d2,sq1,sq2,Zm,Zt);
  {
    size_t tot4=(size_t)Bb*ZB/4;
    size_t totThreads=2*tot4 + (size_t)Bb*ZLD;
    expz_kernel<<<dim3((u32)((totThreads+255)/256)),dim3(256),0,stream>>>(Zm,Zt,Em,Et,euvec,evvec);
  }
  for(int it=0; it<20; ++it){
    sink_gemv<<<dim3((Bb*KP1+3)/4),dim3(256),0,stream>>>(Em, evvec, euvec, uvec);
    sink_gemv<<<dim3((Bb*KP1+3)/4),dim3(256),0,stream>>>(Et, euvec, evvec, vvec);
  }
  size_t tot=(size_t)Bb*KP1*KP1;
  probs_kernel<<<dim3((u32)((tot+255)/256)),dim3(256),0,stream>>>(Zm, uvec, vvec, out + (size_t)2*Bb*Kk*2);
}